// Round 3
// baseline (196.125 us; speedup 1.0000x reference)
//
#include <hip/hip_runtime.h>

typedef float f32x4 __attribute__((ext_vector_type(4)));
typedef __bf16 bf16x8 __attribute__((ext_vector_type(8)));
typedef unsigned short u16x4 __attribute__((ext_vector_type(4)));

__device__ __forceinline__ unsigned short f2bf(float f) {
  union { float f; unsigned int u; } v; v.f = f;
  unsigned int r = (v.u + 0x7FFFu + ((v.u >> 16) & 1u)) >> 16;
  return (unsigned short)r;
}
__device__ __forceinline__ float bf2f(unsigned short h) {
  union { unsigned int u; float f; } v; v.u = ((unsigned int)h) << 16;
  return v.f;
}
__device__ __forceinline__ void gload_lds16(const void* g, void* l) {
  __builtin_amdgcn_global_load_lds(
      (const __attribute__((address_space(1))) unsigned int*)g,
      (__attribute__((address_space(3))) unsigned int*)l, 16, 0, 0);
}

// ---------------- fp32 -> bf16 cast (vectorized) ----------------
__global__ __launch_bounds__(256) void f2bf_kernel(const float* __restrict__ in,
                                                   unsigned short* __restrict__ out,
                                                   int n4) {
  int i = blockIdx.x * 256 + threadIdx.x;
  if (i < n4) {
    float4 v = ((const float4*)in)[i];
    u16x4 o;
    o.x = f2bf(v.x); o.y = f2bf(v.y); o.z = f2bf(v.z); o.w = f2bf(v.w);
    ((u16x4*)out)[i] = o;
  }
}

// ---------------- bf16 GEMM, C = A * B^T  (A: MxK, B: NxK, both K-major) ----
// 128x128 tile, BK=32, 4 waves each computing 64x64 (4x4 fragments of 16x16).
template <bool OUTBF16>
__global__ __launch_bounds__(256) void gemm_bt(const unsigned short* __restrict__ A,
                                               const unsigned short* __restrict__ B,
                                               void* __restrict__ C,
                                               int M, int N, int K) {
  __shared__ unsigned short As[128][32];
  __shared__ unsigned short Bs[128][32];
  const int tid = threadIdx.x;
  const int lane = tid & 63;
  const int w = tid >> 6, wr = w >> 1, wc = w & 1;
  const int bm = blockIdx.y * 128, bn = blockIdx.x * 128;
  const int t4 = tid >> 2, c8 = (tid & 3) * 8;
  const unsigned short* Ab = A + (size_t)(bm + t4) * K + c8;
  const unsigned short* Bb = B + (size_t)(bn + t4) * K + c8;
  const int rq = lane & 15, kg = (lane >> 4) * 8;
  f32x4 acc[4][4] = {};
  for (int kt = 0; kt < K; kt += 32) {
    gload_lds16(Ab + kt,                  &As[t4][c8]);
    gload_lds16(Ab + kt + (size_t)64 * K, &As[t4 + 64][c8]);
    gload_lds16(Bb + kt,                  &Bs[t4][c8]);
    gload_lds16(Bb + kt + (size_t)64 * K, &Bs[t4 + 64][c8]);
    __syncthreads();
    bf16x8 fa[4], fb[4];
#pragma unroll
    for (int m = 0; m < 4; ++m) fa[m] = *(const bf16x8*)&As[wr * 64 + m * 16 + rq][kg];
#pragma unroll
    for (int n = 0; n < 4; ++n) fb[n] = *(const bf16x8*)&Bs[wc * 64 + n * 16 + rq][kg];
#pragma unroll
    for (int m = 0; m < 4; ++m)
#pragma unroll
      for (int n = 0; n < 4; ++n)
        acc[m][n] = __builtin_amdgcn_mfma_f32_16x16x32_bf16(fa[m], fb[n], acc[m][n], 0, 0, 0);
    __syncthreads();
  }
  const int r0 = bm + wr * 64 + (lane >> 4) * 4;
  const int c0 = bn + wc * 64 + rq;
#pragma unroll
  for (int m = 0; m < 4; ++m)
#pragma unroll
    for (int n = 0; n < 4; ++n)
#pragma unroll
      for (int j = 0; j < 4; ++j) {
        int row = r0 + m * 16 + j, col = c0 + n * 16;
        if (OUTBF16)
          ((unsigned short*)C)[(size_t)row * N + col] = f2bf(acc[m][n][j]);
        else
          ((float*)C)[(size_t)row * N + col] = acc[m][n][j];
      }
}

// ---------------- RoPE in-place on q,k thirds of qkv -----------------------
// qkv layout: [(b*T + t)][h*192 + {q:0..63, k:64..127, v:128..191}], bf16.
__global__ __launch_bounds__(256) void rope_inplace(unsigned short* __restrict__ qkv) {
  int idx = blockIdx.x * 256 + threadIdx.x;  // B*H*T*32 = 2M threads
  int dp = idx & 31;
  int t  = (idx >> 5) & 2047;
  int bh = idx >> 16;
  int b = bh >> 4, h = bh & 15;
  unsigned short* p = qkv + (size_t)(b * 2048 + t) * 3072 + h * 192 + dp * 2;
  // theta = 10000^(-dp/32) = 2^(-dp * log2(10000)/32)
  float theta = exp2f(-(float)dp * 0.4152410118609203f);
  float ang = (float)t * theta;
  float sn, cs;
  sincosf(ang, &sn, &cs);
  float q1 = bf2f(p[0]), q2 = bf2f(p[1]);
  p[0] = f2bf(q1 * cs - q2 * sn);
  p[1] = f2bf(q1 * sn + q2 * cs);
  float k1 = bf2f(p[64]), k2 = bf2f(p[65]);
  p[64] = f2bf(k1 * cs - k2 * sn);
  p[65] = f2bf(k1 * sn + k2 * cs);
}

// ---------------- sliding-window attention ---------------------------------
// One 256-thread block per (b, h, 64-row q-tile). Keys slot s=0..319 map to
// j = qbase-256+s (clamped to 0 for staging; masked in scores).
#define WMAX 256
__global__ __launch_bounds__(256) void attn_kernel(const unsigned short* __restrict__ qkv,
                                                   unsigned short* __restrict__ attnb,
                                                   const int* __restrict__ winp) {
  __shared__ unsigned short Qs[64][72];       // +8 pad: 2-way banks on ds_read_b128
  __shared__ unsigned short KPs[320 * 72];    // K tile; later aliased as P[64][328]
  __shared__ unsigned short Vt[64][328];      // V transposed: Vt[d][s]
  const int T = 2048;
  const int tid = threadIdx.x;
  const int bid = blockIdx.x;
  const int qt = bid & 31;
  const int bh = bid >> 5;
  const int b = bh >> 4, h = bh & 15;
  const int qbase = qt * 64;
  const int kbase = qbase - WMAX;
  const int win = *winp;
  const unsigned short* base = qkv + (size_t)b * T * 3072 + h * 192;
  const int tr = tid >> 2, tc = (tid & 3) * 16;
  {  // stage Q (64x64)
    const unsigned short* s = base + (size_t)(qbase + tr) * 3072 + tc;
    *(int4*)&Qs[tr][tc]     = *(const int4*)s;
    *(int4*)&Qs[tr][tc + 8] = *(const int4*)(s + 8);
  }
#pragma unroll
  for (int p5 = 0; p5 < 5; ++p5) {  // stage K (320x64) and V^T
    int s = p5 * 64 + tr;
    int j = kbase + s;
    int jc = j < 0 ? 0 : j;
    const unsigned short* sk = base + (size_t)jc * 3072 + 64 + tc;
    *(int4*)&KPs[s * 72 + tc]     = *(const int4*)sk;
    *(int4*)&KPs[s * 72 + tc + 8] = *(const int4*)(sk + 8);
    const unsigned short* sv = base + (size_t)jc * 3072 + 128 + tc;
    unsigned short tmp[16];
    *(int4*)&tmp[0] = *(const int4*)sv;
    *(int4*)&tmp[8] = *(const int4*)(sv + 8);
#pragma unroll
    for (int e = 0; e < 16; ++e) Vt[tc + e][s] = tmp[e];
  }
  __syncthreads();
  const int lane = tid & 63, wv = tid >> 6;
  const int rbase = wv * 16;  // this wave owns q rows rbase..rbase+15
  const int rq = lane & 15, kg = (lane >> 4) * 8;
  bf16x8 qa[2];
#pragma unroll
  for (int kk = 0; kk < 2; ++kk)
    qa[kk] = *(const bf16x8*)&Qs[rbase + rq][kk * 32 + kg];
  float sc[20][4];
#pragma unroll
  for (int n = 0; n < 20; ++n) {
    f32x4 s = {};
#pragma unroll
    for (int kk = 0; kk < 2; ++kk) {
      bf16x8 kb = *(const bf16x8*)&KPs[(n * 16 + rq) * 72 + kk * 32 + kg];
      s = __builtin_amdgcn_mfma_f32_16x16x32_bf16(qa[kk], kb, s, 0, 0, 0);
    }
#pragma unroll
    for (int r = 0; r < 4; ++r) sc[n][r] = s[r];
  }
  // mask + softmax (rows live in-register; reduce across 16 lanes)
  const float scale = 0.125f;  // 1/sqrt(64)
#pragma unroll
  for (int r = 0; r < 4; ++r) {
    const int i = qbase + rbase + (lane >> 4) * 4 + r;
    float mx = -1e30f;
#pragma unroll
    for (int n = 0; n < 20; ++n) {
      int j = kbase + n * 16 + rq;
      bool valid = (j >= 0) && (j <= i) && (i - j <= win);
      float v = valid ? sc[n][r] * scale : -1e30f;
      sc[n][r] = v;
      mx = fmaxf(mx, v);
    }
#pragma unroll
    for (int off = 1; off < 16; off <<= 1) mx = fmaxf(mx, __shfl_xor(mx, off));
    float sum = 0.f;
#pragma unroll
    for (int n = 0; n < 20; ++n) {
      float pv = __expf(sc[n][r] - mx);
      sc[n][r] = pv;
      sum += pv;
    }
#pragma unroll
    for (int off = 1; off < 16; off <<= 1) sum += __shfl_xor(sum, off);
    float inv = 1.0f / sum;
#pragma unroll
    for (int n = 0; n < 20; ++n) sc[n][r] *= inv;
  }
  __syncthreads();  // all K reads done before KPs is reused as P
#pragma unroll
  for (int n = 0; n < 20; ++n)
#pragma unroll
    for (int r = 0; r < 4; ++r)
      KPs[(rbase + (lane >> 4) * 4 + r) * 328 + n * 16 + rq] = f2bf(sc[n][r]);
  // PV: O(16x64) = P(16x320) * V(320x64), per wave
  f32x4 oacc[4] = {};
#pragma unroll
  for (int kk = 0; kk < 10; ++kk) {
    bf16x8 pa = *(const bf16x8*)&KPs[(rbase + rq) * 328 + kk * 32 + kg];
#pragma unroll
    for (int n = 0; n < 4; ++n) {
      bf16x8 vb = *(const bf16x8*)&Vt[n * 16 + rq][kk * 32 + kg];
      oacc[n] = __builtin_amdgcn_mfma_f32_16x16x32_bf16(pa, vb, oacc[n], 0, 0, 0);
    }
  }
#pragma unroll
  for (int n = 0; n < 4; ++n)
#pragma unroll
    for (int j = 0; j < 4; ++j) {
      int r = qbase + rbase + (lane >> 4) * 4 + j;
      int d = n * 16 + rq;
      attnb[(size_t)(b * T + r) * 1024 + h * 64 + d] = f2bf(oacc[n][j]);
    }
}

// ---------------- launch ----------------------------------------------------
extern "C" void kernel_launch(void* const* d_in, const int* in_sizes, int n_in,
                              void* d_out, int out_size, void* d_ws, size_t ws_size,
                              hipStream_t stream) {
  const float* x    = (const float*)d_in[0];  // (2,2048,1024)
  const float* Wqkv = (const float*)d_in[1];  // (3072,1024)
  const float* Wout = (const float*)d_in[2];  // (1024,1024)
  const int*   winp = (const int*)d_in[3];    // scalar window

  const int M = 4096;        // B*T
  const int C = 1024;
  const int N1 = 3072;       // 3*C
  // ws layout (bf16 elements)
  unsigned short* xb    = (unsigned short*)d_ws;        // 4096*1024
  unsigned short* wqkvb = xb    + (size_t)M * C;        // 3072*1024
  unsigned short* woutb = wqkvb + (size_t)N1 * C;       // 1024*1024
  unsigned short* qkvb  = woutb + (size_t)C * C;        // 4096*3072
  unsigned short* attnb = qkvb  + (size_t)M * N1;       // 4096*1024

  f2bf_kernel<<<(M * C / 4 + 255) / 256, 256, 0, stream>>>(x, xb, M * C / 4);
  f2bf_kernel<<<(N1 * C / 4 + 255) / 256, 256, 0, stream>>>(Wqkv, wqkvb, N1 * C / 4);
  f2bf_kernel<<<(C * C / 4 + 255) / 256, 256, 0, stream>>>(Wout, woutb, C * C / 4);

  dim3 g1(N1 / 128, M / 128);
  gemm_bt<true><<<g1, 256, 0, stream>>>(xb, wqkvb, qkvb, M, N1, C);

  rope_inplace<<<(2 * 16 * 2048 * 32) / 256, 256, 0, stream>>>(qkvb);

  attn_kernel<<<2 * 16 * 32, 256, 0, stream>>>(qkvb, attnb, winp);

  dim3 g2(C / 128, M / 128);
  gemm_bt<false><<<g2, 256, 0, stream>>>(attnb, woutb, (float*)d_out, M, C, C);
}